// Round 5
// baseline (210.249 us; speedup 1.0000x reference)
//
#include <hip/hip_runtime.h>

#define NP 81
#define CC 128
#define HH 128
#define WW 256
#define SX 24            // output x-strip width: 24+9-1 = 32 = ONE B tile
#define NXT 11           // ceil(256/24); last strip is 16 wide (predicated)
#define NBLK (NXT * 16 * 4)   // 704 blocks; 704 % 8 == 0 -> bijective XCD swizzle
#define YPAD 136
#define XPAD 272
#define WS_NEED (4ull * YPAD * XPAD * CC * 2ull)   // 37,879,808 B bf16 t2-transposed

typedef __attribute__((ext_vector_type(8))) short short8;
typedef __attribute__((ext_vector_type(4))) float f32x4;
typedef __attribute__((ext_vector_type(16))) float f32x16;

__device__ __forceinline__ short f2bf(float f) {
    unsigned int u = __builtin_bit_cast(unsigned int, f);
    u += 0x7fffu + ((u >> 16) & 1u);   // round-to-nearest-even
    return (short)(u >> 16);
}

// ---- prepass: t2 fp32 [b][c][h][w] -> ws bf16 [b][yp 136][xp 272][c 128],
// zero-padded halo (y,x offset +4). c-contiguous so the main kernel's B
// fragment = ONE dwordx4 (R4 lesson: 64 scalar dword loads/thread were the
// issue-rate wall at ~4.9 B/cyc/CU). float4 reads -> LDS transpose -> b128
// reads -> dwordx4 writes; all memory ops 16 B wide.
__global__ __launch_bounds__(256) void prepass_t2t(const float* __restrict__ t2,
                                                   short* __restrict__ ws) {
    const int blk = blockIdx.x;            // b*136 + yp
    const int yp  = blk % YPAD;
    const int b   = blk / YPAD;
    const int tid = threadIdx.x;
    short* wrow = ws + (size_t)blk * XPAD * CC;
    const int y2 = yp - 4;
    const short8 z = {0, 0, 0, 0, 0, 0, 0, 0};
    if (y2 < 0 || y2 >= HH) {              // halo row: pure zero fill
        for (int u = tid; u < XPAD * CC / 8; u += 256)
            *(short8*)&wrow[(size_t)u * 8] = z;
        return;
    }
    __shared__ short sT[64 * 136];         // 17.4 KB; stride 136 breaks banks
    {   // x-halo: 16 xp (0..3, 260..271) x 16 octs = exactly 256 zero short8
        const int xh = tid >> 4;
        const int xp = (xh < 4) ? xh : xh + 256;
        *(short8*)&wrow[(size_t)xp * CC + (tid & 15) * 8] = z;
    }
    const int c   = tid & 127;             // this thread's channel (fixed)
    const int x4h = tid >> 7;
    const int oct = tid & 15;
    const int xr  = tid >> 4;
    const float* prow = t2 + ((size_t)(b * CC + c) * HH + y2) * WW;
    for (int ch = 0; ch < 4; ++ch) {       // 4 x-chunks of 64
        const int xbase = ch * 64;
#pragma unroll
        for (int rr = 0; rr < 8; ++rr) {   // 8 float4 per thread
            const int x4 = x4h + 2 * rr;
            const f32x4 vv = *(const f32x4*)&prow[xbase + x4 * 4];
#pragma unroll
            for (int j = 0; j < 4; ++j)    // lanes 0..63 = consecutive c:
                sT[(x4 * 4 + j) * 136 + c] = f2bf(vv[j]);  // 2-way max
        }
        __syncthreads();
#pragma unroll
        for (int r2 = 0; r2 < 4; ++r2) {
            const int x = xr + 16 * r2;
            const short8 vv = *(const short8*)&sT[x * 136 + oct * 8];
            *(short8*)&wrow[(size_t)(xbase + x + 4) * CC + oct * 8] = vv;
        }
        __syncthreads();
    }
}

// ---- main: R3/R4 dataflow (wave w owns t2 row y0-4+w; bre in regs; each
// (y,di) made by exactly one wave), but all loads 16 B wide:
//   B: 8 dwordx4 bf16 from ws (was 64 scalar dword + 64 f2bf; no bounds code,
//      halo pre-zeroed).  A: 6 float4 + element-wise LDS-transpose writes
//      (was 24 scalar dword).  14 VMEM instrs/thread vs 88.
// Live regs ~48 VGPR + 16 AGPR -> chance of 2 blocks/CU (LDS 63.75 KB).
__global__ __launch_bounds__(1024) void corr_main24(
        const float* __restrict__ t1, const short* __restrict__ ws,
        float* __restrict__ out) {
    const int bid = blockIdx.x;
    const int sw  = (bid & 7) * (NBLK / 8) + (bid >> 3);  // XCD-contiguous
    const int ys = sw & 15;
    const int v  = sw >> 4;
    const int xt = v % NXT;
    const int b  = v / NXT;
    const int X0 = xt * SX;
    const int y0 = ys * 8;

    const int tid  = threadIdx.x;
    const int lane = tid & 63;
    const int w    = tid >> 6;        // 0..15: owns t2 row y0-4+w
    const int n    = lane & 31;       // MFMA A-row m / B-col n index
    const int g    = lane >> 5;       // k-group

    __shared__ short sA[8 * SX * 128];            // 48 KB, XOR-swizzled
    __shared__ __align__(16) float obufs[16 * 9 * 28];  // 15.75 KB

    // ---- B: 8 bf16 dwordx4, c-contiguous, issued first (latency hides
    // under the whole A-stage; drained by the barrier's vmcnt anyway)
    const short* bp = ws + ((size_t)(b * YPAD + y0 + w) * XPAD + X0 + n) * CC
                    + g * 8;
    short8 bre[8];
#pragma unroll
    for (int kc = 0; kc < 8; ++kc)
        bre[kc] = *(const short8*)&bp[kc * 16];

    // ---- A: float4 along x + in-LDS transpose into the verified swizzled
    // layout (element b16 writes; layout identical to R3/R4's short8 path)
#pragma unroll
    for (int i = 0; i < 6; ++i) {
        const int idx = tid + i * 1024;           // 6144 = 6 x4 * 128 c * 8 yy
        const int x4 = idx % 6;
        const int vv = idx / 6;
        const int c  = vv & 127;
        const int yy = vv >> 7;
        const int xg = X0 + x4 * 4;
        f32x4 t = {0.f, 0.f, 0.f, 0.f};
        if (xg < WW)
            t = *(const f32x4*)&t1[((size_t)(b * CC + c) * HH + y0 + yy) * WW + xg];
        const int oct = c >> 3;
#pragma unroll
        for (int j = 0; j < 4; ++j) {
            const int x = x4 * 4 + j;
            sA[yy * 3072 + x * 128 + ((oct ^ (x & 15)) * 8 + (c & 7))] = f2bf(t[j]);
        }
    }
    __syncthreads();

    const int ylo = (w > 8) ? (w - 8) : 0;
    const int yhi = (w < 7) ? w : 7;
    float* ob = &obufs[w * 252];                  // [9 dj][28] f32, per wave

    for (int yy = ylo; yy <= yhi; ++yy) {
        const int sbase = yy * 3072 + n * 128;

        f32x16 a;
#pragma unroll
        for (int q = 0; q < 16; ++q) a[q] = 0.f;
#pragma unroll
        for (int kc = 0; kc < 8; ++kc) {
            const short8 af = *(const short8*)
                &sA[sbase + (((kc * 2 + g) ^ (n & 15)) * 8)];
            a = __builtin_amdgcn_mfma_f32_32x32x16_bf16(af, bre[kc], a, 0, 0, 0);
        }

        // band extract: D(row m = x offset, col n) -> dj = n - m
#pragma unroll
        for (int q = 0; q < 16; ++q) {
            const int m  = (q & 3) + 8 * (q >> 2) + 4 * g;
            const int dj = n - m;
            if (dj >= 0 && dj <= 8 && m < SX) ob[dj * 28 + m] = a[q];
        }

        // coalesced stores: 9 dj rows x 24 x = 54 f32x4
        const int di = w - yy;
        const int y  = y0 + yy;
        if (lane < 54) {
            const int dj = lane / 6, xq = lane % 6;
            if (X0 + xq * 4 < WW) {
                f32x4 vv = *(const f32x4*)&ob[dj * 28 + xq * 4];
                *(f32x4*)&out[((size_t)(b * NP + di * 9 + dj) * HH + y) * WW
                              + X0 + xq * 4] = vv;
            }
        }
    }
}

// ---------------- fallback (proven R4 kernel, 83 us) if ws too small --------
__global__ __launch_bounds__(1024) void corr_fallback(
        const float* __restrict__ t1, const float* __restrict__ t2,
        float* __restrict__ out) {
    const int bid = blockIdx.x;
    const int sw  = (bid & 7) * (NBLK / 8) + (bid >> 3);
    const int ys = sw & 15;
    const int v  = sw >> 4;
    const int xt = v % NXT;
    const int b  = v / NXT;
    const int X0 = xt * SX;
    const int y0 = ys * 8;
    const int tid  = threadIdx.x;
    const int lane = tid & 63;
    const int w    = tid >> 6;
    const int n    = lane & 31;
    const int g    = lane >> 5;
    __shared__ short sA[8 * SX * 128];
    __shared__ __align__(16) float obufs[16 * 9 * 28];
    const size_t plane = (size_t)HH * WW;
    const int r = y0 - 4 + w;
#pragma unroll
    for (int i = 0; i < 3; ++i) {
        const int unit = tid + i * 1024;
        const int x    = unit % SX;
        const int rest = unit / SX;
        const int oct  = rest & 15;
        const int yy   = rest >> 4;
        short8 pk = {0,0,0,0,0,0,0,0};
        if (X0 + x < WW) {
            const float* p = t1 + ((size_t)(b * CC + oct * 8) * HH + (y0 + yy)) * WW
                           + X0 + x;
#pragma unroll
            for (int j = 0; j < 8; ++j) pk[j] = f2bf(p[(size_t)j * plane]);
        }
        *(short8*)&sA[yy * (SX * 128) + x * 128 + ((oct ^ (x & 15)) * 8)] = pk;
    }
    __syncthreads();
    const int x2 = X0 - 4 + n;
    const bool ok = (r >= 0) && (r < HH) && (x2 >= 0) && (x2 < WW);
    const int rc  = r  < 0 ? 0 : (r  > HH - 1 ? HH - 1 : r);
    const int xc  = x2 < 0 ? 0 : (x2 > WW - 1 ? WW - 1 : x2);
    const float* bp = t2 + ((size_t)(b * CC + g * 8) * HH + rc) * WW + xc;
    short8 bre[8];
#pragma unroll
    for (int kc = 0; kc < 8; ++kc) {
        short8 f;
#pragma unroll
        for (int j = 0; j < 8; ++j) f[j] = f2bf(bp[(size_t)(kc * 16 + j) * plane]);
        if (!ok) f = (short8){0,0,0,0,0,0,0,0};
        bre[kc] = f;
    }
    const int ylo = (w > 8) ? (w - 8) : 0;
    const int yhi = (w < 7) ? w : 7;
    float* ob = &obufs[w * 252];
    for (int yy = ylo; yy <= yhi; ++yy) {
        const int sbase = yy * (SX * 128) + n * 128;
        f32x16 a;
#pragma unroll
        for (int q = 0; q < 16; ++q) a[q] = 0.f;
#pragma unroll
        for (int kc = 0; kc < 8; ++kc) {
            const short8 af = *(const short8*)
                &sA[sbase + (((kc * 2 + g) ^ (n & 15)) * 8)];
            a = __builtin_amdgcn_mfma_f32_32x32x16_bf16(af, bre[kc], a, 0, 0, 0);
        }
#pragma unroll
        for (int q = 0; q < 16; ++q) {
            const int m  = (q & 3) + 8 * (q >> 2) + 4 * g;
            const int dj = n - m;
            if (dj >= 0 && dj <= 8 && m < SX) ob[dj * 28 + m] = a[q];
        }
        const int di = w - yy;
        const int y  = y0 + yy;
        if (lane < 54) {
            const int dj = lane / 6, xq = lane % 6;
            if (X0 + xq * 4 < WW) {
                f32x4 vv = *(const f32x4*)&ob[dj * 28 + xq * 4];
                *(f32x4*)&out[((size_t)(b * NP + di * 9 + dj) * HH + y) * WW
                              + X0 + xq * 4] = vv;
            }
        }
    }
}

extern "C" void kernel_launch(void* const* d_in, const int* in_sizes, int n_in,
                              void* d_out, int out_size, void* d_ws, size_t ws_size,
                              hipStream_t stream) {
    const float* t1 = (const float*)d_in[0];
    const float* t2 = (const float*)d_in[1];
    if (ws_size >= WS_NEED) {
        short* ws = (short*)d_ws;
        prepass_t2t<<<4 * YPAD, 256, 0, stream>>>(t2, ws);
        corr_main24<<<NBLK, 1024, 0, stream>>>(t1, ws, (float*)d_out);
    } else {
        corr_fallback<<<NBLK, 1024, 0, stream>>>(t1, t2, (float*)d_out);
    }
}

// Round 7
// 194.806 us; speedup vs baseline: 1.0793x; 1.0793x over previous
//
#include <hip/hip_runtime.h>

#define NP 81
#define CC 128
#define HH 128
#define WW 256
#define YPAD 136
#define XPAD 272
#define WS_NEED (4ull * YPAD * XPAD * CC * 2ull)   // 37,879,808 B bf16 t2-transposed

#define SX 16             // output x-strip width (16 | 256: no x bounds checks)
#define NBLK 1024         // 16 xt * 16 ys * 4 b = exactly 2 rounds of 512 (2 blk/CU)

typedef __attribute__((ext_vector_type(4))) short bf16x4;   // NOTE: 'short4' is taken by HIP
typedef __attribute__((ext_vector_type(8))) short short8;
typedef __attribute__((ext_vector_type(4))) float f32x4;
typedef __attribute__((ext_vector_type(16))) float f32x16;

__device__ __forceinline__ short f2bf(float f) {
    unsigned int u = __builtin_bit_cast(unsigned int, f);
    u += 0x7fffu + ((u >> 16) & 1u);   // round-to-nearest-even
    return (short)(u >> 16);
}

// ---- prepass: t2 fp32 [b][c][h][w] -> ws bf16 [b][yp136][xp272][c128],
// halo zero-padded. R5 lesson: the LDS-transpose version ran ~40 us
// (ds_write_b16 + 8 barriers + 8.5 waves/CU). This version has NO LDS and
// NO barriers: each thread reads 8 float4 from 8 consecutive c-planes (same
// x-quad) and writes 4 c-contiguous short8 -- all VMEM 16 B wide, in-thread
// transpose. Grid 1088 (c-halves split) = 17 waves/CU for latency hiding.
__global__ __launch_bounds__(256) void prepass_t2t(const float* __restrict__ t2,
                                                   short* __restrict__ ws) {
    const int blk = blockIdx.x;            // (b*136 + yp)*2 + hf
    const int hf  = blk & 1;
    const int row = blk >> 1;
    const int yp  = row % YPAD;
    const int b   = row / YPAD;
    const int tid = threadIdx.x;
    short* wrow = ws + (size_t)row * XPAD * CC;
    const int y2 = yp - 4;
    const short8 z = {0,0,0,0,0,0,0,0};
    if (y2 < 0 || y2 >= HH) {              // halo row: pure zero fill (split)
        for (int u = tid + hf * 2176; u < 2176 + hf * 2176; u += 256)
            *(short8*)&wrow[(size_t)u * 8] = z;
        return;
    }
    if (tid < 128) {                       // x-halo: 16 cols x 16 octs, split
        const int idx = hf * 8 + (tid >> 4);            // 0..15
        const int xp  = (idx < 4) ? idx : idx + 256;    // 0..3, 260..271
        *(short8*)&wrow[(size_t)xp * CC + (tid & 15) * 8] = z;
    }
    const size_t plane = (size_t)HH * WW;
#pragma unroll
    for (int i = 0; i < 2; ++i) {
        const int u   = tid + i * 256;     // 512 units = 8 oct x 64 xq
        const int oct = hf * 8 + (u & 7);
        const int xq  = u >> 3;            // 0..63
        const float* p = t2 + ((size_t)(b * CC + oct * 8) * HH + y2) * WW + xq * 4;
        f32x4 v[8];
#pragma unroll
        for (int j = 0; j < 8; ++j) v[j] = *(const f32x4*)&p[(size_t)j * plane];
#pragma unroll
        for (int jj = 0; jj < 4; ++jj) {
            short8 s;
#pragma unroll
            for (int j = 0; j < 8; ++j) s[j] = f2bf(v[j][jj]);
            *(short8*)&wrow[(size_t)(4 + xq * 4 + jj) * CC + oct * 8] = s;
        }
    }
}

// ---- main: R3/R5 dataflow (wave w owns t2 row y0-4+w, bre in regs, each
// (y,di) made by exactly one wave, band extract). R6 changes:
//  * SX 24 -> 16: NBLK=1024 = exactly 2 residency rounds of 512 (tail gone),
//    no x bounds checks anywhere (16 | 256).
//  * A-stage in-thread transpose: 8 float4 (two halves of 4 to cap liveness)
//    -> swizzled ds_write_b64; kills R5's 24 scalar ds_write_b16/thread
//    (bank conflicts 1.41M -> 2.49M was that signature).
//  * B: 8 dwordx4 from ws issued first (latency hides under A-stage).
// Live regs ~55 VGPR + 16 AGPR -> 2 blocks/CU (LDS 43.3 KB).
__global__ __launch_bounds__(1024) void corr_main16(
        const float* __restrict__ t1, const short* __restrict__ ws,
        float* __restrict__ out) {
    const int bid = blockIdx.x;
    const int sw  = (bid & 7) * (NBLK / 8) + (bid >> 3);  // XCD-contiguous
    const int xt = sw & 15;
    const int ys = (sw >> 4) & 15;
    const int b  = sw >> 8;
    const int X0 = xt * SX;
    const int y0 = ys * 8;

    const int tid  = threadIdx.x;
    const int lane = tid & 63;
    const int w    = tid >> 6;        // 0..15: owns t2 row y0-4+w
    const int n    = lane & 31;       // MFMA A-row m / B-col n index
    const int g    = lane >> 5;       // k-group

    __shared__ short sA[8 * SX * 128];                  // 32 KB, XOR-swizzled
    __shared__ __align__(16) float obufs[16 * 9 * 20];  // 11.25 KB

    // ---- B: 8 bf16 dwordx4, c-contiguous, issued first
    const short* bp = ws + ((size_t)(b * YPAD + y0 + w) * XPAD + X0 + n) * CC
                    + g * 8;
    short8 bre[8];
#pragma unroll
    for (int kc = 0; kc < 8; ++kc)
        bre[kc] = *(const short8*)&bp[kc * 16];

    // ---- A: in-thread transpose. 512 units = 8 yy x 4 xq x 16 oct;
    // thread reads 4 c-planes at a time (f32x4 each), writes bf16x4 (b64)
    // into the verified swizzled layout. Conflict-free: per store, each
    // 256-B x-row is densely covered by its 16 oct-lanes.
    if (tid < 512) {
        const int oct = tid & 15;
        const int xq  = (tid >> 4) & 3;
        const int yy  = tid >> 6;
        const size_t plane = (size_t)HH * WW;
        const float* p = t1 + ((size_t)(b * CC + oct * 8) * HH + y0 + yy) * WW
                       + X0 + xq * 4;
#pragma unroll
        for (int h = 0; h < 2; ++h) {
            f32x4 v[4];
#pragma unroll
            for (int j = 0; j < 4; ++j)
                v[j] = *(const f32x4*)&p[(size_t)(h * 4 + j) * plane];
#pragma unroll
            for (int jj = 0; jj < 4; ++jj) {
                const int x = xq * 4 + jj;
                bf16x4 s;
#pragma unroll
                for (int j = 0; j < 4; ++j) s[j] = f2bf(v[j][jj]);
                *(bf16x4*)&sA[yy * 2048 + x * 128 + ((oct ^ x) * 8) + h * 4] = s;
            }
        }
    }
    __syncthreads();

    const int ylo = (w > 8) ? (w - 8) : 0;
    const int yhi = (w < 7) ? w : 7;
    float* ob = &obufs[w * 180];                  // [9 dj][20] f32, per wave

    for (int yy = ylo; yy <= yhi; ++yy) {
        const int sbase = yy * 2048 + n * 128;

        f32x16 a;
#pragma unroll
        for (int q = 0; q < 16; ++q) a[q] = 0.f;
#pragma unroll
        for (int kc = 0; kc < 8; ++kc) {
            const short8 af = *(const short8*)
                &sA[sbase + (((kc * 2 + g) ^ (n & 15)) * 8)];
            a = __builtin_amdgcn_mfma_f32_32x32x16_bf16(af, bre[kc], a, 0, 0, 0);
        }

        // band extract: D(row m = x offset, col n) -> dj = n - m
#pragma unroll
        for (int q = 0; q < 16; ++q) {
            const int m  = (q & 3) + 8 * (q >> 2) + 4 * g;
            const int dj = n - m;
            if (dj >= 0 && dj <= 8 && m < SX) ob[dj * 20 + m] = a[q];
        }

        // coalesced stores: 9 dj rows x 16 x = 36 f32x4
        const int di = w - yy;
        const int y  = y0 + yy;
        if (lane < 36) {
            const int dj = lane >> 2, xq = lane & 3;
            f32x4 vv = *(const f32x4*)&ob[dj * 20 + xq * 4];
            *(f32x4*)&out[((size_t)(b * NP + di * 9 + dj) * HH + y) * WW
                          + X0 + xq * 4] = vv;
        }
    }
}

// ---------------- fallback (proven R4 kernel, 83 us) if ws too small --------
#define FB_SX 24
#define FB_NXT 11
#define FB_NBLK (FB_NXT * 16 * 4)
__global__ __launch_bounds__(1024) void corr_fallback(
        const float* __restrict__ t1, const float* __restrict__ t2,
        float* __restrict__ out) {
    const int bid = blockIdx.x;
    const int sw  = (bid & 7) * (FB_NBLK / 8) + (bid >> 3);
    const int ys = sw & 15;
    const int v  = sw >> 4;
    const int xt = v % FB_NXT;
    const int b  = v / FB_NXT;
    const int X0 = xt * FB_SX;
    const int y0 = ys * 8;
    const int tid  = threadIdx.x;
    const int lane = tid & 63;
    const int w    = tid >> 6;
    const int n    = lane & 31;
    const int g    = lane >> 5;
    __shared__ short sA[8 * FB_SX * 128];
    __shared__ __align__(16) float obufs[16 * 9 * 28];
    const size_t plane = (size_t)HH * WW;
    const int r = y0 - 4 + w;
#pragma unroll
    for (int i = 0; i < 3; ++i) {
        const int unit = tid + i * 1024;
        const int x    = unit % FB_SX;
        const int rest = unit / FB_SX;
        const int oct  = rest & 15;
        const int yy   = rest >> 4;
        short8 pk = {0,0,0,0,0,0,0,0};
        if (X0 + x < WW) {
            const float* p = t1 + ((size_t)(b * CC + oct * 8) * HH + (y0 + yy)) * WW
                           + X0 + x;
#pragma unroll
            for (int j = 0; j < 8; ++j) pk[j] = f2bf(p[(size_t)j * plane]);
        }
        *(short8*)&sA[yy * (FB_SX * 128) + x * 128 + ((oct ^ (x & 15)) * 8)] = pk;
    }
    __syncthreads();
    const int x2 = X0 - 4 + n;
    const bool ok = (r >= 0) && (r < HH) && (x2 >= 0) && (x2 < WW);
    const int rc  = r  < 0 ? 0 : (r  > HH - 1 ? HH - 1 : r);
    const int xc  = x2 < 0 ? 0 : (x2 > WW - 1 ? WW - 1 : x2);
    const float* bp = t2 + ((size_t)(b * CC + g * 8) * HH + rc) * WW + xc;
    short8 bre[8];
#pragma unroll
    for (int kc = 0; kc < 8; ++kc) {
        short8 f;
#pragma unroll
        for (int j = 0; j < 8; ++j) f[j] = f2bf(bp[(size_t)(kc * 16 + j) * plane]);
        if (!ok) f = (short8){0,0,0,0,0,0,0,0};
        bre[kc] = f;
    }
    const int ylo = (w > 8) ? (w - 8) : 0;
    const int yhi = (w < 7) ? w : 7;
    float* ob = &obufs[w * 252];
    for (int yy = ylo; yy <= yhi; ++yy) {
        const int sbase = yy * (FB_SX * 128) + n * 128;
        f32x16 a;
#pragma unroll
        for (int q = 0; q < 16; ++q) a[q] = 0.f;
#pragma unroll
        for (int kc = 0; kc < 8; ++kc) {
            const short8 af = *(const short8*)
                &sA[sbase + (((kc * 2 + g) ^ (n & 15)) * 8)];
            a = __builtin_amdgcn_mfma_f32_32x32x16_bf16(af, bre[kc], a, 0, 0, 0);
        }
#pragma unroll
        for (int q = 0; q < 16; ++q) {
            const int m  = (q & 3) + 8 * (q >> 2) + 4 * g;
            const int dj = n - m;
            if (dj >= 0 && dj <= 8 && m < FB_SX) ob[dj * 28 + m] = a[q];
        }
        const int di = w - yy;
        const int y  = y0 + yy;
        if (lane < 54) {
            const int dj = lane / 6, xq = lane % 6;
            if (X0 + xq * 4 < WW) {
                f32x4 vv = *(const f32x4*)&ob[dj * 28 + xq * 4];
                *(f32x4*)&out[((size_t)(b * NP + di * 9 + dj) * HH + y) * WW
                              + X0 + xq * 4] = vv;
            }
        }
    }
}

extern "C" void kernel_launch(void* const* d_in, const int* in_sizes, int n_in,
                              void* d_out, int out_size, void* d_ws, size_t ws_size,
                              hipStream_t stream) {
    const float* t1 = (const float*)d_in[0];
    const float* t2 = (const float*)d_in[1];
    if (ws_size >= WS_NEED) {
        short* ws = (short*)d_ws;
        prepass_t2t<<<4 * YPAD * 2, 256, 0, stream>>>(t2, ws);
        corr_main16<<<NBLK, 1024, 0, stream>>>(t1, ws, (float*)d_out);
    } else {
        corr_fallback<<<FB_NBLK, 1024, 0, stream>>>(t1, t2, (float*)d_out);
    }
}

// Round 8
// 190.698 us; speedup vs baseline: 1.1025x; 1.0215x over previous
//
#include <hip/hip_runtime.h>

#define NP 81
#define CC 128
#define HH 128
#define WW 256
#define YPAD 136
#define XPAD 272
#define WS_NEED (4ull * YPAD * XPAD * CC * 2ull)   // 37,879,808 B bf16 t2-transposed

#define SX 16             // output x-strip width (16 | 256: no x bounds checks)
#define NBLK 512          // 16 xt * 8 ypairs * 4 b; 2 strips of 8 y per block

typedef __attribute__((ext_vector_type(4))) short bf16x4;   // 'short4' is taken by HIP
typedef __attribute__((ext_vector_type(8))) short short8;
typedef __attribute__((ext_vector_type(4))) float f32x4;
typedef __attribute__((ext_vector_type(16))) float f32x16;

__device__ __forceinline__ short f2bf(float f) {
    unsigned int u = __builtin_bit_cast(unsigned int, f);
    u += 0x7fffu + ((u >> 16) & 1u);   // round-to-nearest-even
    return (short)(u >> 16);
}

// ---- prepass: t2 fp32 [b][c][h][w] -> ws bf16 [b][yp136][xp272][c128],
// halo zero-padded. No LDS, no barriers: in-thread transpose, all VMEM 16 B.
__global__ __launch_bounds__(256) void prepass_t2t(const float* __restrict__ t2,
                                                   short* __restrict__ ws) {
    const int blk = blockIdx.x;            // (b*136 + yp)*2 + hf
    const int hf  = blk & 1;
    const int row = blk >> 1;
    const int yp  = row % YPAD;
    const int b   = row / YPAD;
    const int tid = threadIdx.x;
    short* wrow = ws + (size_t)row * XPAD * CC;
    const int y2 = yp - 4;
    const short8 z = {0,0,0,0,0,0,0,0};
    if (y2 < 0 || y2 >= HH) {              // halo row: pure zero fill (split)
        for (int u = tid + hf * 2176; u < 2176 + hf * 2176; u += 256)
            *(short8*)&wrow[(size_t)u * 8] = z;
        return;
    }
    if (tid < 128) {                       // x-halo: 16 cols x 16 octs, split
        const int idx = hf * 8 + (tid >> 4);            // 0..15
        const int xp  = (idx < 4) ? idx : idx + 256;    // 0..3, 260..271
        *(short8*)&wrow[(size_t)xp * CC + (tid & 15) * 8] = z;
    }
    const size_t plane = (size_t)HH * WW;
#pragma unroll
    for (int i = 0; i < 2; ++i) {
        const int u   = tid + i * 256;     // 512 units = 8 oct x 64 xq
        const int oct = hf * 8 + (u & 7);
        const int xq  = u >> 3;            // 0..63
        const float* p = t2 + ((size_t)(b * CC + oct * 8) * HH + y2) * WW + xq * 4;
        f32x4 v[8];
#pragma unroll
        for (int j = 0; j < 8; ++j) v[j] = *(const f32x4*)&p[(size_t)j * plane];
#pragma unroll
        for (int jj = 0; jj < 4; ++jj) {
            short8 s;
#pragma unroll
            for (int j = 0; j < 8; ++j) s[j] = f2bf(v[j][jj]);
            *(short8*)&wrow[(size_t)(4 + xq * 4 + jj) * CC + oct * 8] = s;
        }
    }
}

// ---- main: balanced strip-pair schedule. Block = (b, 16-x strip, 16-y
// super-strip = two 8-row strips). 16 waves. Strip0: wave w owns band
// position p=w (rows y0-4+w). Strip1: wave w owns p=(w+8)&15.
// Identity: iters(w) = c(w) + c((w+8)&15) = 9 for ALL w (c = triangular
// count [1..8,8..1]) -> no tail (R7 lesson: the triangular tail ran 40% of
// block time at <=25% occupancy). For w>=8 the strip1 row EQUALS the strip0
// row (bre reused, no reload); w<8 reloads bre after its short strip0 work
// (bubble hidden by 31 other waves). Both strips' sA staged before ONE
// barrier. LDS 75.25 KB -> 2 blocks/CU; regs stay at R7's ~44 VGPR shape.
__global__ __launch_bounds__(1024) void corr_bal(
        const float* __restrict__ t1, const short* __restrict__ ws,
        float* __restrict__ out) {
    const int bid = blockIdx.x;
    const int sw  = (bid & 7) * (NBLK / 8) + (bid >> 3);  // XCD-contiguous
    const int xt  = sw & 15;
    const int yp8 = (sw >> 4) & 7;
    const int b   = sw >> 7;
    const int X0 = xt * SX;
    const int y0 = yp8 * 16;

    const int tid  = threadIdx.x;
    const int lane = tid & 63;
    const int w    = tid >> 6;        // 0..15
    const int n    = lane & 31;       // MFMA A-row m / B-col n index
    const int g    = lane >> 5;       // k-group

    __shared__ short sA[2][8 * SX * 128];               // 2 x 32 KB, swizzled
    __shared__ __align__(16) float obufs[16 * 9 * 20];  // 11.25 KB

    // ---- B strip0: row r0 = y0-4+w -> ws row y0+w. 8 dwordx4, issued first.
    const short* bp0 = ws + ((size_t)(b * YPAD + y0 + w) * XPAD + X0 + n) * CC
                     + g * 8;
    short8 bre[8];
#pragma unroll
    for (int kc = 0; kc < 8; ++kc) bre[kc] = *(const short8*)&bp0[kc * 16];

    // ---- A: stage BOTH strips (tid<512 -> strip0 rows, tid>=512 -> strip1),
    // in-thread transpose, swizzled b64 writes (R7-verified layout).
    {
        const int sid  = tid & 511;
        const int half = tid >> 9;
        const int oct = sid & 15;
        const int xq  = (sid >> 4) & 3;
        const int yy  = sid >> 6;
        const size_t plane = (size_t)HH * WW;
        const float* p = t1 + ((size_t)(b * CC + oct * 8) * HH
                               + y0 + half * 8 + yy) * WW + X0 + xq * 4;
        short* sAh = sA[half];
#pragma unroll
        for (int h = 0; h < 2; ++h) {
            f32x4 v[4];
#pragma unroll
            for (int j = 0; j < 4; ++j)
                v[j] = *(const f32x4*)&p[(size_t)(h * 4 + j) * plane];
#pragma unroll
            for (int jj = 0; jj < 4; ++jj) {
                const int x = xq * 4 + jj;
                bf16x4 s;
#pragma unroll
                for (int j = 0; j < 4; ++j) s[j] = f2bf(v[j][jj]);
                *(bf16x4*)&sAh[yy * 2048 + x * 128 + ((oct ^ x) * 8) + h * 4] = s;
            }
        }
    }
    __syncthreads();

    float* ob = &obufs[w * 180];                  // [9 dj][20] f32, per wave

    auto run = [&](const short* sAs, int p, int ybase) {
        const int ylo = (p > 8) ? (p - 8) : 0;
        const int yhi = (p < 7) ? p : 7;
        for (int yy = ylo; yy <= yhi; ++yy) {
            const int sbase = yy * 2048 + n * 128;
            f32x16 a;
#pragma unroll
            for (int q = 0; q < 16; ++q) a[q] = 0.f;
#pragma unroll
            for (int kc = 0; kc < 8; ++kc) {
                const short8 af = *(const short8*)
                    &sAs[sbase + (((kc * 2 + g) ^ (n & 15)) * 8)];
                a = __builtin_amdgcn_mfma_f32_32x32x16_bf16(af, bre[kc], a, 0, 0, 0);
            }
            // band extract: D(row m = x offset, col n) -> dj = n - m
#pragma unroll
            for (int q = 0; q < 16; ++q) {
                const int m  = (q & 3) + 8 * (q >> 2) + 4 * g;
                const int dj = n - m;
                if (dj >= 0 && dj <= 8 && m < SX) ob[dj * 20 + m] = a[q];
            }
            const int di = p - yy;
            const int y  = ybase + yy;
            if (lane < 36) {                     // 9 dj x 16 x = 36 f32x4
                const int dj = lane >> 2, xq = lane & 3;
                f32x4 vv = *(const f32x4*)&ob[dj * 20 + xq * 4];
                *(f32x4*)&out[((size_t)(b * NP + di * 9 + dj) * HH + y) * WW
                              + X0 + xq * 4] = vv;
            }
        }
    };

    run(sA[0], w, y0);                           // strip0: c(w) iters

    if (w < 8) {
        // reload bre for strip1 rows y0+12+w (ws row y0+16+w). The asm
        // barrier stops the compiler hoisting these loads above strip0
        // (a second live bre set would blow the 64-reg budget -> R1 spill).
        asm volatile("" ::: "memory");
        const short* bp1 = ws + ((size_t)(b * YPAD + y0 + 16 + w) * XPAD
                                 + X0 + n) * CC + g * 8;
#pragma unroll
        for (int kc = 0; kc < 8; ++kc) bre[kc] = *(const short8*)&bp1[kc * 16];
    }

    run(sA[1], (w + 8) & 15, y0 + 8);            // strip1: c((w+8)&15) iters
}

// ---------------- fallback (proven R4 kernel, 83 us) if ws too small --------
#define FB_SX 24
#define FB_NXT 11
#define FB_NBLK (FB_NXT * 16 * 4)
__global__ __launch_bounds__(1024) void corr_fallback(
        const float* __restrict__ t1, const float* __restrict__ t2,
        float* __restrict__ out) {
    const int bid = blockIdx.x;
    const int sw  = (bid & 7) * (FB_NBLK / 8) + (bid >> 3);
    const int ys = sw & 15;
    const int v  = sw >> 4;
    const int xt = v % FB_NXT;
    const int b  = v / FB_NXT;
    const int X0 = xt * FB_SX;
    const int y0 = ys * 8;
    const int tid  = threadIdx.x;
    const int lane = tid & 63;
    const int w    = tid >> 6;
    const int n    = lane & 31;
    const int g    = lane >> 5;
    __shared__ short sAf[8 * FB_SX * 128];
    __shared__ __align__(16) float obufsf[16 * 9 * 28];
    const size_t plane = (size_t)HH * WW;
    const int r = y0 - 4 + w;
#pragma unroll
    for (int i = 0; i < 3; ++i) {
        const int unit = tid + i * 1024;
        const int x    = unit % FB_SX;
        const int rest = unit / FB_SX;
        const int oct  = rest & 15;
        const int yy   = rest >> 4;
        short8 pk = {0,0,0,0,0,0,0,0};
        if (X0 + x < WW) {
            const float* p = t1 + ((size_t)(b * CC + oct * 8) * HH + (y0 + yy)) * WW
                           + X0 + x;
#pragma unroll
            for (int j = 0; j < 8; ++j) pk[j] = f2bf(p[(size_t)j * plane]);
        }
        *(short8*)&sAf[yy * (FB_SX * 128) + x * 128 + ((oct ^ (x & 15)) * 8)] = pk;
    }
    __syncthreads();
    const int x2 = X0 - 4 + n;
    const bool ok = (r >= 0) && (r < HH) && (x2 >= 0) && (x2 < WW);
    const int rc  = r  < 0 ? 0 : (r  > HH - 1 ? HH - 1 : r);
    const int xc  = x2 < 0 ? 0 : (x2 > WW - 1 ? WW - 1 : x2);
    const float* bp = t2 + ((size_t)(b * CC + g * 8) * HH + rc) * WW + xc;
    short8 bre[8];
#pragma unroll
    for (int kc = 0; kc < 8; ++kc) {
        short8 f;
#pragma unroll
        for (int j = 0; j < 8; ++j) f[j] = f2bf(bp[(size_t)(kc * 16 + j) * plane]);
        if (!ok) f = (short8){0,0,0,0,0,0,0,0};
        bre[kc] = f;
    }
    const int ylo = (w > 8) ? (w - 8) : 0;
    const int yhi = (w < 7) ? w : 7;
    float* ob = &obufsf[w * 252];
    for (int yy = ylo; yy <= yhi; ++yy) {
        const int sbase = yy * (FB_SX * 128) + n * 128;
        f32x16 a;
#pragma unroll
        for (int q = 0; q < 16; ++q) a[q] = 0.f;
#pragma unroll
        for (int kc = 0; kc < 8; ++kc) {
            const short8 af = *(const short8*)
                &sAf[sbase + (((kc * 2 + g) ^ (n & 15)) * 8)];
            a = __builtin_amdgcn_mfma_f32_32x32x16_bf16(af, bre[kc], a, 0, 0, 0);
        }
#pragma unroll
        for (int q = 0; q < 16; ++q) {
            const int m  = (q & 3) + 8 * (q >> 2) + 4 * g;
            const int dj = n - m;
            if (dj >= 0 && dj <= 8 && m < FB_SX) ob[dj * 28 + m] = a[q];
        }
        const int di = w - yy;
        const int y  = y0 + yy;
        if (lane < 54) {
            const int dj = lane / 6, xq = lane % 6;
            if (X0 + xq * 4 < WW) {
                f32x4 vv = *(const f32x4*)&ob[dj * 28 + xq * 4];
                *(f32x4*)&out[((size_t)(b * NP + di * 9 + dj) * HH + y) * WW
                              + X0 + xq * 4] = vv;
            }
        }
    }
}

extern "C" void kernel_launch(void* const* d_in, const int* in_sizes, int n_in,
                              void* d_out, int out_size, void* d_ws, size_t ws_size,
                              hipStream_t stream) {
    const float* t1 = (const float*)d_in[0];
    const float* t2 = (const float*)d_in[1];
    if (ws_size >= WS_NEED) {
        short* ws = (short*)d_ws;
        prepass_t2t<<<4 * YPAD * 2, 256, 0, stream>>>(t2, ws);
        corr_bal<<<NBLK, 1024, 0, stream>>>(t1, ws, (float*)d_out);
    } else {
        corr_fallback<<<FB_NBLK, 1024, 0, stream>>>(t1, t2, (float*)d_out);
    }
}

// Round 9
// 189.125 us; speedup vs baseline: 1.1117x; 1.0083x over previous
//
#include <hip/hip_runtime.h>

#define NP 81
#define CC 128
#define HH 128
#define WW 256
#define YPAD 136
#define XPAD 272
#define WS_NEED (4ull * YPAD * XPAD * CC * 2ull)   // 37,879,808 B bf16 t2-transposed

#define SX 16             // output x-strip width (16 | 256: no x bounds checks)
#define NBLK 512          // 16 xt * 8 ypairs * 4 b; 2 strips of 8 y per block

typedef __attribute__((ext_vector_type(4))) short bf16x4;   // 'short4' is taken by HIP
typedef __attribute__((ext_vector_type(8))) short short8;
typedef __attribute__((ext_vector_type(4))) float f32x4;
typedef __attribute__((ext_vector_type(16))) float f32x16;

__device__ __forceinline__ short f2bf(float f) {
    unsigned int u = __builtin_bit_cast(unsigned int, f);
    u += 0x7fffu + ((u >> 16) & 1u);   // round-to-nearest-even
    return (short)(u >> 16);
}

// ws layout (R9): [b][row 136][oct 16][xp 272][c8]  (oct = kc*2 + g)
// -> a wave's B-fragment load (lanes n=0..31 x g=0..1, fixed kc) is two
// contiguous 512-B runs: 100% line efficiency. R8's c-contiguous layout had
// lane stride 256 B = one 64-B line PER LANE with 16 B used (25%), which
// made the prologue burst drain at ~3 TB/s and dominated the kernel.
#define WSROW (16 * XPAD * 8)          // shorts per (b,row)

// ---- prepass: t2 fp32 [b][c][h][w] -> ws bf16 (layout above), halo
// zero-padded. No LDS, no barriers, in-thread transpose. R9: lane decode
// puts xq in the LOW bits so each read instr is 1 KB contiguous (was oct
// in low bits = plane-strided lanes = 25% line efficiency).
__global__ __launch_bounds__(256) void prepass_t2t(const float* __restrict__ t2,
                                                   short* __restrict__ ws) {
    const int blk = blockIdx.x;            // (b*136 + yp)*2 + hf
    const int hf  = blk & 1;
    const int row = blk >> 1;
    const int yp  = row % YPAD;
    const int b   = row / YPAD;
    const int tid = threadIdx.x;
    short* wrow = ws + (size_t)row * WSROW;
    const int y2 = yp - 4;
    const short8 z = {0,0,0,0,0,0,0,0};
    if (y2 < 0 || y2 >= HH) {              // halo row: pure zero fill (split)
        for (int u = tid + hf * 2176; u < 2176 + hf * 2176; u += 256)
            *(short8*)&wrow[(size_t)u * 8] = z;
        return;
    }
    if (tid < 128) {                       // x-halo: 16 cols x 16 octs, split
        const int idx = hf * 8 + (tid >> 4);            // 0..15
        const int xp  = (idx < 4) ? idx : idx + 256;    // 0..3, 260..271
        *(short8*)&wrow[(size_t)((tid & 15) * XPAD + xp) * 8] = z;
    }
    const size_t plane = (size_t)HH * WW;
#pragma unroll
    for (int i = 0; i < 2; ++i) {
        const int u    = tid + i * 256;    // 512 units = 64 xq (fast) x 8 oct
        const int xq   = u & 63;           // LOW bits: contiguous lanes
        const int oct  = hf * 8 + (u >> 6);
        const float* p = t2 + ((size_t)(b * CC + oct * 8) * HH + y2) * WW + xq * 4;
        f32x4 v[8];
#pragma unroll
        for (int j = 0; j < 8; ++j) v[j] = *(const f32x4*)&p[(size_t)j * plane];
#pragma unroll
        for (int jj = 0; jj < 4; ++jj) {
            short8 s;
#pragma unroll
            for (int j = 0; j < 8; ++j) s[j] = f2bf(v[j][jj]);
            *(short8*)&wrow[(size_t)(oct * XPAD + 4 + xq * 4 + jj) * 8] = s;
        }
    }
}

// ---- main: R8's balanced strip-pair schedule, unchanged except the two
// access-pattern fixes (ws layout + A-stage lane decode).
__global__ __launch_bounds__(1024) void corr_bal(
        const float* __restrict__ t1, const short* __restrict__ ws,
        float* __restrict__ out) {
    const int bid = blockIdx.x;
    const int sw  = (bid & 7) * (NBLK / 8) + (bid >> 3);  // XCD-contiguous
    const int xt  = sw & 15;
    const int yp8 = (sw >> 4) & 7;
    const int b   = sw >> 7;
    const int X0 = xt * SX;
    const int y0 = yp8 * 16;

    const int tid  = threadIdx.x;
    const int lane = tid & 63;
    const int w    = tid >> 6;        // 0..15
    const int n    = lane & 31;       // MFMA A-row m / B-col n index
    const int g    = lane >> 5;       // k-group

    __shared__ short sA[2][8 * SX * 128];               // 2 x 32 KB, swizzled
    __shared__ __align__(16) float obufs[16 * 9 * 20];  // 11.25 KB

    // ---- B strip0: row y0+w. Per kc: two contiguous 512-B runs (new layout).
    const short* bp0 = ws + ((size_t)(b * YPAD + y0 + w) * 16 + g) * (XPAD * 8)
                     + (size_t)(X0 + n) * 8;
    short8 bre[8];
#pragma unroll
    for (int kc = 0; kc < 8; ++kc)
        bre[kc] = *(const short8*)&bp0[(size_t)kc * (XPAD * 16)];

    // ---- A: stage BOTH strips; xq in LOW lane bits (4 lanes = one 64-B
    // line of t1). In-thread transpose, swizzled b64 writes (R7 layout).
    {
        const int sid  = tid & 511;
        const int half = tid >> 9;
        const int xq  = sid & 3;           // LOW bits: line-contiguous
        const int oct = (sid >> 2) & 15;
        const int yy  = sid >> 6;
        const size_t plane = (size_t)HH * WW;
        const float* p = t1 + ((size_t)(b * CC + oct * 8) * HH
                               + y0 + half * 8 + yy) * WW + X0 + xq * 4;
        short* sAh = sA[half];
#pragma unroll
        for (int h = 0; h < 2; ++h) {
            f32x4 v[4];
#pragma unroll
            for (int j = 0; j < 4; ++j)
                v[j] = *(const f32x4*)&p[(size_t)(h * 4 + j) * plane];
#pragma unroll
            for (int jj = 0; jj < 4; ++jj) {
                const int x = xq * 4 + jj;
                bf16x4 s;
#pragma unroll
                for (int j = 0; j < 4; ++j) s[j] = f2bf(v[j][jj]);
                *(bf16x4*)&sAh[yy * 2048 + x * 128 + ((oct ^ x) * 8) + h * 4] = s;
            }
        }
    }
    __syncthreads();

    float* ob = &obufs[w * 180];                  // [9 dj][20] f32, per wave

    auto run = [&](const short* sAs, int p, int ybase) {
        const int ylo = (p > 8) ? (p - 8) : 0;
        const int yhi = (p < 7) ? p : 7;
        for (int yy = ylo; yy <= yhi; ++yy) {
            const int sbase = yy * 2048 + n * 128;
            f32x16 a;
#pragma unroll
            for (int q = 0; q < 16; ++q) a[q] = 0.f;
#pragma unroll
            for (int kc = 0; kc < 8; ++kc) {
                const short8 af = *(const short8*)
                    &sAs[sbase + (((kc * 2 + g) ^ (n & 15)) * 8)];
                a = __builtin_amdgcn_mfma_f32_32x32x16_bf16(af, bre[kc], a, 0, 0, 0);
            }
            // band extract: D(row m = x offset, col n) -> dj = n - m
#pragma unroll
            for (int q = 0; q < 16; ++q) {
                const int m  = (q & 3) + 8 * (q >> 2) + 4 * g;
                const int dj = n - m;
                if (dj >= 0 && dj <= 8 && m < SX) ob[dj * 20 + m] = a[q];
            }
            const int di = p - yy;
            const int y  = ybase + yy;
            if (lane < 36) {                     // 9 dj x 16 x = 36 f32x4
                const int dj = lane >> 2, xq = lane & 3;
                f32x4 vv = *(const f32x4*)&ob[dj * 20 + xq * 4];
                *(f32x4*)&out[((size_t)(b * NP + di * 9 + dj) * HH + y) * WW
                              + X0 + xq * 4] = vv;
            }
        }
    };

    run(sA[0], w, y0);                           // strip0: c(w) iters

    if (w < 8) {
        // reload bre for strip1 (ws row y0+16+w). asm barrier: keep ONE live
        // bre set (a second would blow the 64-reg budget -> R1 spill).
        asm volatile("" ::: "memory");
        const short* bp1 = ws + ((size_t)(b * YPAD + y0 + 16 + w) * 16 + g)
                               * (XPAD * 8) + (size_t)(X0 + n) * 8;
#pragma unroll
        for (int kc = 0; kc < 8; ++kc)
            bre[kc] = *(const short8*)&bp1[(size_t)kc * (XPAD * 16)];
    }

    run(sA[1], (w + 8) & 15, y0 + 8);            // strip1: c((w+8)&15) iters
}

// ---------------- fallback (proven R4 kernel, 83 us) if ws too small --------
#define FB_SX 24
#define FB_NXT 11
#define FB_NBLK (FB_NXT * 16 * 4)
__global__ __launch_bounds__(1024) void corr_fallback(
        const float* __restrict__ t1, const float* __restrict__ t2,
        float* __restrict__ out) {
    const int bid = blockIdx.x;
    const int sw  = (bid & 7) * (FB_NBLK / 8) + (bid >> 3);
    const int ys = sw & 15;
    const int v  = sw >> 4;
    const int xt = v % FB_NXT;
    const int b  = v / FB_NXT;
    const int X0 = xt * FB_SX;
    const int y0 = ys * 8;
    const int tid  = threadIdx.x;
    const int lane = tid & 63;
    const int w    = tid >> 6;
    const int n    = lane & 31;
    const int g    = lane >> 5;
    __shared__ short sAf[8 * FB_SX * 128];
    __shared__ __align__(16) float obufsf[16 * 9 * 28];
    const size_t plane = (size_t)HH * WW;
    const int r = y0 - 4 + w;
#pragma unroll
    for (int i = 0; i < 3; ++i) {
        const int unit = tid + i * 1024;
        const int x    = unit % FB_SX;
        const int rest = unit / FB_SX;
        const int oct  = rest & 15;
        const int yy   = rest >> 4;
        short8 pk = {0,0,0,0,0,0,0,0};
        if (X0 + x < WW) {
            const float* p = t1 + ((size_t)(b * CC + oct * 8) * HH + (y0 + yy)) * WW
                           + X0 + x;
#pragma unroll
            for (int j = 0; j < 8; ++j) pk[j] = f2bf(p[(size_t)j * plane]);
        }
        *(short8*)&sAf[yy * (FB_SX * 128) + x * 128 + ((oct ^ (x & 15)) * 8)] = pk;
    }
    __syncthreads();
    const int x2 = X0 - 4 + n;
    const bool ok = (r >= 0) && (r < HH) && (x2 >= 0) && (x2 < WW);
    const int rc  = r  < 0 ? 0 : (r  > HH - 1 ? HH - 1 : r);
    const int xc  = x2 < 0 ? 0 : (x2 > WW - 1 ? WW - 1 : x2);
    const float* bp = t2 + ((size_t)(b * CC + g * 8) * HH + rc) * WW + xc;
    short8 bre[8];
#pragma unroll
    for (int kc = 0; kc < 8; ++kc) {
        short8 f;
#pragma unroll
        for (int j = 0; j < 8; ++j) f[j] = f2bf(bp[(size_t)(kc * 16 + j) * plane]);
        if (!ok) f = (short8){0,0,0,0,0,0,0,0};
        bre[kc] = f;
    }
    const int ylo = (w > 8) ? (w - 8) : 0;
    const int yhi = (w < 7) ? w : 7;
    float* ob = &obufsf[w * 252];
    for (int yy = ylo; yy <= yhi; ++yy) {
        const int sbase = yy * (FB_SX * 128) + n * 128;
        f32x16 a;
#pragma unroll
        for (int q = 0; q < 16; ++q) a[q] = 0.f;
#pragma unroll
        for (int kc = 0; kc < 8; ++kc) {
            const short8 af = *(const short8*)
                &sAf[sbase + (((kc * 2 + g) ^ (n & 15)) * 8)];
            a = __builtin_amdgcn_mfma_f32_32x32x16_bf16(af, bre[kc], a, 0, 0, 0);
        }
#pragma unroll
        for (int q = 0; q < 16; ++q) {
            const int m  = (q & 3) + 8 * (q >> 2) + 4 * g;
            const int dj = n - m;
            if (dj >= 0 && dj <= 8 && m < FB_SX) ob[dj * 28 + m] = a[q];
        }
        const int di = w - yy;
        const int y  = y0 + yy;
        if (lane < 54) {
            const int dj = lane / 6, xq = lane % 6;
            if (X0 + xq * 4 < WW) {
                f32x4 vv = *(const f32x4*)&ob[dj * 28 + xq * 4];
                *(f32x4*)&out[((size_t)(b * NP + di * 9 + dj) * HH + y) * WW
                              + X0 + xq * 4] = vv;
            }
        }
    }
}

extern "C" void kernel_launch(void* const* d_in, const int* in_sizes, int n_in,
                              void* d_out, int out_size, void* d_ws, size_t ws_size,
                              hipStream_t stream) {
    const float* t1 = (const float*)d_in[0];
    const float* t2 = (const float*)d_in[1];
    if (ws_size >= WS_NEED) {
        short* ws = (short*)d_ws;
        prepass_t2t<<<4 * YPAD * 2, 256, 0, stream>>>(t2, ws);
        corr_bal<<<NBLK, 1024, 0, stream>>>(t1, ws, (float*)d_out);
    } else {
        corr_fallback<<<FB_NBLK, 1024, 0, stream>>>(t1, t2, (float*)d_out);
    }
}